// Round 1
// baseline (66.691 us; speedup 1.0000x reference)
//
#include <hip/hip_runtime.h>
#include <hip/hip_bf16.h>

// out[i] = W[idx[i] - 1], idx in [1, 200]. Pure gather, memory-bound.
// Stage the 200-entry table in LDS; 4 elements per thread via int4/float4.

#define TABLE_SIZE 200

__global__ __launch_bounds__(256) void fapb_gather_kernel(
    const int* __restrict__ idx, const float* __restrict__ W,
    float* __restrict__ out, int n /* total elements, multiple handled below */) {
    __shared__ float sW[TABLE_SIZE];
    for (int i = threadIdx.x; i < TABLE_SIZE; i += blockDim.x) sW[i] = W[i];
    __syncthreads();

    int i = (blockIdx.x * blockDim.x + threadIdx.x) * 4;
    if (i + 3 < n) {
        int4 v = *reinterpret_cast<const int4*>(idx + i);
        float4 o;
        o.x = sW[v.x - 1];
        o.y = sW[v.y - 1];
        o.z = sW[v.z - 1];
        o.w = sW[v.w - 1];
        *reinterpret_cast<float4*>(out + i) = o;
    } else {
        for (; i < n; ++i) out[i] = sW[idx[i] - 1];
    }
}

extern "C" void kernel_launch(void* const* d_in, const int* in_sizes, int n_in,
                              void* d_out, int out_size, void* d_ws, size_t ws_size,
                              hipStream_t stream) {
    const int*   idx = (const int*)d_in[0];   // inputs [B, S], int32, values in [1, 200]
    const float* W   = (const float*)d_in[1]; // [200, 1] float32
    float*       out = (float*)d_out;         // [B, S, 1] float32

    int n = out_size;                         // 16384 * 200 = 3,276,800
    int threads = 256;
    int elems_per_block = threads * 4;
    int blocks = (n + elems_per_block - 1) / elems_per_block;

    fapb_gather_kernel<<<blocks, threads, 0, stream>>>(idx, W, out, n);
}

// Round 2
// 65.476 us; speedup vs baseline: 1.0186x; 1.0186x over previous
//
#include <hip/hip_runtime.h>
#include <hip/hip_bf16.h>

// out[i] = W[idx[i] - 1], idx in [1, 200]. Pure gather, memory-bound.
// Stage the 200-entry table in LDS; 8 elements per thread via 2x int4/float4.
// R1 note: dur_us=66.7 but rocprof shows top dispatches are 42us harness
// 0xAA fills (268MB) -- our kernel is <42us (est ~5us). This round: halve
// block count (8 elem/thread) to test whether dur_us is harness-floor-bound.

#define TABLE_SIZE 200

__global__ __launch_bounds__(256) void fapb_gather8_kernel(
    const int* __restrict__ idx, const float* __restrict__ W,
    float* __restrict__ out, int n) {
    __shared__ float sW[TABLE_SIZE];
    if (threadIdx.x < TABLE_SIZE) sW[threadIdx.x] = W[threadIdx.x];
    __syncthreads();

    int i = (blockIdx.x * blockDim.x + threadIdx.x) * 8;
    if (i + 7 < n) {
        const int4* p = reinterpret_cast<const int4*>(idx + i);
        int4 a = p[0];
        int4 b = p[1];
        float4 o0, o1;
        o0.x = sW[a.x - 1];
        o0.y = sW[a.y - 1];
        o0.z = sW[a.z - 1];
        o0.w = sW[a.w - 1];
        o1.x = sW[b.x - 1];
        o1.y = sW[b.y - 1];
        o1.z = sW[b.z - 1];
        o1.w = sW[b.w - 1];
        float4* q = reinterpret_cast<float4*>(out + i);
        q[0] = o0;
        q[1] = o1;
    } else {
        for (; i < n; ++i) out[i] = sW[idx[i] - 1];
    }
}

extern "C" void kernel_launch(void* const* d_in, const int* in_sizes, int n_in,
                              void* d_out, int out_size, void* d_ws, size_t ws_size,
                              hipStream_t stream) {
    const int*   idx = (const int*)d_in[0];   // inputs [B, S], int32, values in [1, 200]
    const float* W   = (const float*)d_in[1]; // [200, 1] float32
    float*       out = (float*)d_out;         // [B, S, 1] float32

    int n = out_size;                         // 16384 * 200 = 3,276,800
    int threads = 256;
    int elems_per_block = threads * 8;        // 2048
    int blocks = (n + elems_per_block - 1) / elems_per_block;  // 1600

    fapb_gather8_kernel<<<blocks, threads, 0, stream>>>(idx, W, out, n);
}